// Round 5
// baseline (206.440 us; speedup 1.0000x reference)
//
#include <hip/hip_runtime.h>
#include <math.h>

#define B 16
#define N 10000
#define E 160000
#define CAP 96   // per-dst bucket capacity; deg ~ Poisson(16), P(deg>96) ~ 0

// float -> bf16 (RNE) stored as ushort
__device__ __forceinline__ ushort f2bf(float v) {
    uint u = __float_as_uint(v);
    u = (u + 0x7fffu + ((u >> 16) & 1u)) >> 16;
    return (ushort)u;
}
__device__ __forceinline__ float bf2f(ushort u) { return __uint_as_float(((uint)u) << 16); }
__device__ __forceinline__ float bf2f_lo(uint u) { return __uint_as_float(u << 16); }
__device__ __forceinline__ float bf2f_hi(uint u) { return __uint_as_float(u & 0xffff0000u); }
// bucket payload: (ew_q18 << 14) | src ; decode with midpoint
__device__ __forceinline__ float dec_ew(uint u) {
    return ((float)(u >> 14) + 0.5f) * (1.0f / 262144.0f);
}

// ---------------------------------------------------------------------------
// Prep: edge bucketing (atomics) + per-row precompute for layer 1:
//   y[r=n*16+b][o]  = sum_c amp[c]*x[n,b,c]*w1[32+c][o]   (bf16, 16 o)
//   xpart[r][o]     = sum_c x[n,b,c]*w1[c][o] + b1[o]     (fp32, 16 o)
//   gi[r], gj[r]    = gate dots (as before)
// This algebraically absorbs agg_dense1's entire dense phase (out = xpart +
// inv * sum_k coef * y[src_k]) -> layer-1 kernel has no matmul, no weight
// staging, and a half-width gather (512B/edge vs 1KB).
// 16x16 tiles: thread tid owns row r = n0*16+tid -> all stores coalesced.
// ---------------------------------------------------------------------------
__global__ __launch_bounds__(256)
void prep_bucket_kernel(const float* __restrict__ X,
                        const float* __restrict__ gate_w1,   // (65)
                        const float* __restrict__ amp_w1,    // (32)
                        const float* __restrict__ b1,        // (16)
                        const int* __restrict__ ei1, const float* __restrict__ ew1,
                        const int* __restrict__ ei2, const float* __restrict__ ew2,
                        const float* __restrict__ w1,        // (64,16)
                        const float* __restrict__ w2,        // (32,32)
                        ushort* __restrict__ yt,             // (N*16,16) bf16
                        float* __restrict__ xpart,           // (N*16,16) fp32
                        float* __restrict__ gi, float* __restrict__ gj,
                        float* __restrict__ w2T,
                        int* __restrict__ bcount1, uint* __restrict__ bucket1,
                        int* __restrict__ bcount2, uint* __restrict__ bucket2) {
    __shared__ __align__(16) float s_w1[64 * 16];    // 4 KB, [c][o]
    int tid = threadIdx.x;
    {   // stage w1 (1024 floats, 4 per thread)
        int i = tid * 4;
        *(float4*)&s_w1[i] = *(const float4*)&w1[i];
    }
    __syncthreads();

    int gtid = blockIdx.x * 256 + tid;
    int gs = gridDim.x * 256;

    for (int t = gtid; t < 2 * E; t += gs) {
        if (t < E) {
            int d = ei1[E + t];
            int pos = atomicAdd(&bcount1[d], 1);
            if (pos < CAP) {
                uint q = (uint)(ew1[t] * 262144.0f);
                if (q > 262143u) q = 262143u;
                bucket1[d * CAP + pos] = (q << 14) | (uint)ei1[t];
            }
        } else {
            int e = t - E;
            int d = ei2[E + e];
            int pos = atomicAdd(&bcount2[d], 1);
            if (pos < CAP) {
                uint q = (uint)(ew2[e] * 262144.0f);
                if (q > 262143u) q = 262143u;
                bucket2[d * CAP + pos] = (q << 14) | (uint)ei2[e];
            }
        }
    }

    // weight transpose for layer 2: w2T[o][kk] (32x32)
    if (gtid < 1024) {
        w2T[(gtid & 31) * 32 + (gtid >> 5)] = w2[gtid];
    }

    // 16-node x 16-batch tiles: one row per thread, coalesced outputs.
    for (int tile = blockIdx.x; tile < N / 16; tile += gridDim.x) {
        int n0 = tile * 16;
        int nl = tid >> 4, b = tid & 15;
        int n = n0 + nl;
        const float4* xr4 = (const float4*)(X + ((size_t)b * N + n) * 32);
        float4 xr[8];
        #pragma unroll
        for (int q = 0; q < 8; ++q) xr[q] = xr4[q];
        const float* xs = (const float*)xr;

        float pi = 0.f, pj = 0.f;
        #pragma unroll
        for (int q = 0; q < 8; ++q) {
            float4 v = xr[q];
            pi += v.x * gate_w1[4*q]   + v.y * gate_w1[4*q+1]
                + v.z * gate_w1[4*q+2] + v.w * gate_w1[4*q+3];
            pj += v.x * gate_w1[32+4*q]   + v.y * gate_w1[32+4*q+1]
                + v.z * gate_w1[32+4*q+2] + v.w * gate_w1[32+4*q+3];
        }

        float po[16], py[16];
        #pragma unroll
        for (int o = 0; o < 16; ++o) { po[o] = b1[o]; py[o] = 0.f; }
        #pragma unroll
        for (int c = 0; c < 32; ++c) {
            float xa = xs[c];
            float ya = amp_w1[c] * xa;
            const float4* wa = (const float4*)&s_w1[c * 16];
            const float4* wb = (const float4*)&s_w1[(32 + c) * 16];
            #pragma unroll
            for (int q = 0; q < 4; ++q) {
                float4 a = wa[q], bb = wb[q];
                po[4*q]   += xa * a.x;  py[4*q]   += ya * bb.x;
                po[4*q+1] += xa * a.y;  py[4*q+1] += ya * bb.y;
                po[4*q+2] += xa * a.z;  py[4*q+2] += ya * bb.z;
                po[4*q+3] += xa * a.w;  py[4*q+3] += ya * bb.w;
            }
        }

        int r = n0 * 16 + tid;                     // == n*16 + b
        uint pk[8];
        #pragma unroll
        for (int j = 0; j < 8; ++j)
            pk[j] = (uint)f2bf(py[2*j]) | ((uint)f2bf(py[2*j+1]) << 16);
        uint4* yd = (uint4*)(yt + (size_t)r * 16);
        yd[0] = make_uint4(pk[0], pk[1], pk[2], pk[3]);
        yd[1] = make_uint4(pk[4], pk[5], pk[6], pk[7]);
        float4* xd = (float4*)(xpart + (size_t)r * 16);
        #pragma unroll
        for (int q = 0; q < 4; ++q)
            xd[q] = make_float4(po[4*q], po[4*q+1], po[4*q+2], po[4*q+3]);
        gi[r] = pi; gj[r] = pj;
    }
}

// ---------------------------------------------------------------------------
// Fused layer 1 (y-precompute form): one node per block, 256 threads.
// Phases: [eb+gi stage | coef | gather y + h-reduce | register epilogue].
// No weights, no X, no dense matmul, 6.6 KB LDS. Gather: lane (og=l&1 8-o
// slice, b=4wv+((l>>1)&3), h=l>>3 slot-depth 8); wave reads 128B contiguous
// per slot (4 b x 16 o bf16).
// ---------------------------------------------------------------------------
__global__ __launch_bounds__(256, 8)
void agg1_kernel(const uint4* __restrict__ y4,      // (N*16,16) bf16 as uint4 x2/row
                 const float* __restrict__ xpart,   // (N*16,16) fp32
                 const float* __restrict__ gi,
                 const float* __restrict__ gj,
                 const int* __restrict__ bcount,
                 const uint* __restrict__ bucket,
                 const float* __restrict__ gate_w,   // (65), [64]=wge
                 const float* __restrict__ gate_b,
                 const float* __restrict__ gate_w2,  // (33)
                 ushort* __restrict__ htb,
                 float* __restrict__ gi2, float* __restrict__ gj2) {
    __shared__ uint  s_eb[CAP];
    __shared__ float s_coef[CAP * 16];                // 6 KB
    __shared__ float s_gi[16];

    int n = blockIdx.x;
    int tid = threadIdx.x;

    int cnt = bcount[n];
    int deg = cnt < CAP ? cnt : CAP;
    if (tid < CAP / 4)
        ((uint4*)s_eb)[tid] = ((const uint4*)(bucket + (size_t)n * CAP))[tid];
    if (tid < 16) s_gi[tid] = gi[n * 16 + tid] + gate_b[0];
    __syncthreads();

    // coef[k][b] = ew * sigmoid(gi + gj + ew*wge + gb)
    float wge = gate_w[64];
    for (int p = tid; p < deg * 16; p += 256) {
        int k = p >> 4, b = p & 15;
        uint pr = s_eb[k];
        float w = dec_ew(pr);
        float z = s_gi[b] + gj[(pr & 0x3FFFu) * 16 + b] + w * wge;
        s_coef[p] = w / (1.0f + __expf(-z));
    }
    __syncthreads();

    // gather y: acc[o] = sum_k coef[k,b] * y[src_k, b, o-slice]
    int wv = tid >> 6, l = tid & 63;
    int og = l & 1;                        // o-slice: 8*og .. 8*og+7
    int b  = 4 * wv + ((l >> 1) & 3);      // 0..15
    int h  = l >> 3;                       // slot offset 0..7
    uint boff = (uint)b * 2 + og;          // uint4 idx within 32B row pair
    float a0 = 0.f, a1 = 0.f, a2 = 0.f, a3 = 0.f;
    float a4 = 0.f, a5 = 0.f, a6 = 0.f, a7 = 0.f;
    for (int k = h; k < deg; k += 8) {
        uint pr = s_eb[k];
        float cc = s_coef[(k << 4) | b];
        uint4 u = y4[(pr & 0x3FFFu) * 32u + boff];
        a0 += cc * bf2f_lo(u.x); a1 += cc * bf2f_hi(u.x);
        a2 += cc * bf2f_lo(u.y); a3 += cc * bf2f_hi(u.y);
        a4 += cc * bf2f_lo(u.z); a5 += cc * bf2f_hi(u.z);
        a6 += cc * bf2f_lo(u.w); a7 += cc * bf2f_hi(u.w);
    }
    // reduce over h (lane bits 3,4,5)
    a0 += __shfl_xor(a0, 8, 64); a0 += __shfl_xor(a0, 16, 64); a0 += __shfl_xor(a0, 32, 64);
    a1 += __shfl_xor(a1, 8, 64); a1 += __shfl_xor(a1, 16, 64); a1 += __shfl_xor(a1, 32, 64);
    a2 += __shfl_xor(a2, 8, 64); a2 += __shfl_xor(a2, 16, 64); a2 += __shfl_xor(a2, 32, 64);
    a3 += __shfl_xor(a3, 8, 64); a3 += __shfl_xor(a3, 16, 64); a3 += __shfl_xor(a3, 32, 64);
    a4 += __shfl_xor(a4, 8, 64); a4 += __shfl_xor(a4, 16, 64); a4 += __shfl_xor(a4, 32, 64);
    a5 += __shfl_xor(a5, 8, 64); a5 += __shfl_xor(a5, 16, 64); a5 += __shfl_xor(a5, 32, 64);
    a6 += __shfl_xor(a6, 8, 64); a6 += __shfl_xor(a6, 16, 64); a6 += __shfl_xor(a6, 32, 64);
    a7 += __shfl_xor(a7, 8, 64); a7 += __shfl_xor(a7, 16, 64); a7 += __shfl_xor(a7, 32, 64);

    if (h == 0) {   // 8 lanes/wave: 4 b x 2 og
        float inv = 1.0f / fmaxf((float)cnt, 1.0f);
        size_t xb = ((size_t)n * 16 + b) * 16 + 8 * og;
        float4 xp0 = *(const float4*)&xpart[xb];
        float4 xp1 = *(const float4*)&xpart[xb + 4];
        float v0 = xp0.x + inv * a0, v1 = xp0.y + inv * a1;
        float v2 = xp0.z + inv * a2, v3 = xp0.w + inv * a3;
        float v4 = xp1.x + inv * a4, v5 = xp1.y + inv * a5;
        float v6 = xp1.z + inv * a6, v7 = xp1.w + inv * a7;
        v0 = v0 > 0.f ? v0 : 0.01f * v0;  v1 = v1 > 0.f ? v1 : 0.01f * v1;
        v2 = v2 > 0.f ? v2 : 0.01f * v2;  v3 = v3 > 0.f ? v3 : 0.01f * v3;
        v4 = v4 > 0.f ? v4 : 0.01f * v4;  v5 = v5 > 0.f ? v5 : 0.01f * v5;
        v6 = v6 > 0.f ? v6 : 0.01f * v6;  v7 = v7 > 0.f ? v7 : 0.01f * v7;
        uint4 pk;
        pk.x = (uint)f2bf(v0) | ((uint)f2bf(v1) << 16);
        pk.y = (uint)f2bf(v2) | ((uint)f2bf(v3) << 16);
        pk.z = (uint)f2bf(v4) | ((uint)f2bf(v5) << 16);
        pk.w = (uint)f2bf(v6) | ((uint)f2bf(v7) << 16);
        ((uint4*)htb)[(size_t)n * 32 + boff] = pk;
        int ob = 8 * og;
        float pi = v0 * gate_w2[ob]     + v1 * gate_w2[ob + 1]
                 + v2 * gate_w2[ob + 2] + v3 * gate_w2[ob + 3]
                 + v4 * gate_w2[ob + 4] + v5 * gate_w2[ob + 5]
                 + v6 * gate_w2[ob + 6] + v7 * gate_w2[ob + 7];
        float pj = v0 * gate_w2[16 + ob]     + v1 * gate_w2[16 + ob + 1]
                 + v2 * gate_w2[16 + ob + 2] + v3 * gate_w2[16 + ob + 3]
                 + v4 * gate_w2[16 + ob + 4] + v5 * gate_w2[16 + ob + 5]
                 + v6 * gate_w2[16 + ob + 6] + v7 * gate_w2[16 + ob + 7];
        pi += __shfl_xor(pi, 1, 64);
        pj += __shfl_xor(pj, 1, 64);
        if (og == 0) { gi2[n * 16 + b] = pi; gj2[n * 16 + b] = pj; }
    }
}

// ---------------------------------------------------------------------------
// Fused layer 2: one node per block, 256 threads, uint4 gather with 4 loads
// in flight (unchanged from R4).
// ---------------------------------------------------------------------------
__global__ __launch_bounds__(256, 8)
void agg_dense2_kernel(const uint4* __restrict__ htb4,    // bf16x8 (16B)
                       const float* __restrict__ gi,
                       const float* __restrict__ gj,
                       const int* __restrict__ bcount,
                       const uint* __restrict__ bucket,
                       const float* __restrict__ gate_w,   // (33), [32]=wge
                       const float* __restrict__ gate_b,
                       const float* __restrict__ amp_w,    // (16)
                       const float* __restrict__ w2T,      // (32,32) [o][kk]
                       const float* __restrict__ b2,       // (32)
                       float* __restrict__ out) {
    __shared__ uint  s_eb[CAP];
    __shared__ float s_coef[CAP * 16];
    __shared__ float s_gi[16];
    __shared__ __align__(16) float s_x[16][20];       // row 80B: b128-able
    __shared__ __align__(16) float s_feat[16][20];
    __shared__ __align__(16) float s_wmT[32 * 36];    // [o][kk], row 144B

    int n = blockIdx.x;
    int tid = threadIdx.x;

    int cnt = bcount[n];
    int deg = cnt < CAP ? cnt : CAP;
    if (tid < CAP / 4)
        ((uint4*)s_eb)[tid] = ((const uint4*)(bucket + (size_t)n * CAP))[tid];
    {   // w2T staging: 256 float4 loads
        int o = tid >> 3, k4 = tid & 7;
        *(float4*)&s_wmT[o * 36 + k4 * 4] = ((const float4*)w2T)[o * 8 + k4];
    }
    if (tid < 32) {   // self features: 32 uint4 loads, decode to fp32 LDS
        uint4 u = htb4[(size_t)n * 32 + tid];
        int b = tid >> 1, cb = (tid & 1) * 8;
        float4 f0, f1;
        f0.x = bf2f_lo(u.x); f0.y = bf2f_hi(u.x);
        f0.z = bf2f_lo(u.y); f0.w = bf2f_hi(u.y);
        f1.x = bf2f_lo(u.z); f1.y = bf2f_hi(u.z);
        f1.z = bf2f_lo(u.w); f1.w = bf2f_hi(u.w);
        *(float4*)&s_x[b][cb]     = f0;
        *(float4*)&s_x[b][cb + 4] = f1;
    }
    if (tid < 16) s_gi[tid] = gi[n * 16 + tid] + gate_b[0];
    __syncthreads();

    float wge = gate_w[32];
    for (int p = tid; p < deg * 16; p += 256) {
        int k = p >> 4, b = p & 15;
        uint pr = s_eb[k];
        float w = dec_ew(pr);
        float z = s_gi[b] + gj[(pr & 0x3FFFu) * 16 + b] + w * wge;
        s_coef[p] = w / (1.0f + __expf(-z));
    }
    __syncthreads();

    // Gather: c8=l&1, b=4*wv+((l>>1)&3), qd=l>>3 (slot depth 8), stride 32.
    int wv = tid >> 6, l = tid & 63;
    int c8 = l & 1;                        // channel group: 8c8..8c8+7
    int b  = 4 * wv + ((l >> 1) & 3);      // 0..15
    int qd = l >> 3;                       // slot offset 0..7
    uint boff = (uint)b * 2 + c8;          // uint4 idx within 512B node block
    float a0 = 0.f, a1 = 0.f, a2 = 0.f, a3 = 0.f;
    float a4 = 0.f, a5 = 0.f, a6 = 0.f, a7 = 0.f;
    int k = qd;
    for (; k + 8 < deg; k += 32) {         // slots k, k+8 valid; k+16, k+24 masked
        bool v2 = (k + 16) < deg, v3 = (k + 24) < deg;
        uint i2 = v2 ? (uint)(k + 16) : 0u;
        uint i3 = v3 ? (uint)(k + 24) : 0u;
        uint p0 = s_eb[k], p1 = s_eb[k + 8], p2 = s_eb[i2], p3 = s_eb[i3];
        float c0 = s_coef[(k << 4) | b];
        float c1 = s_coef[((k + 8) << 4) | b];
        float c2 = s_coef[(i2 << 4) | b]; if (!v2) c2 = 0.f;
        float c3 = s_coef[(i3 << 4) | b]; if (!v3) c3 = 0.f;
        uint4 u0 = htb4[(p0 & 0x3FFFu) * 32u + boff];
        uint4 u1 = htb4[(p1 & 0x3FFFu) * 32u + boff];
        uint4 u2 = htb4[(p2 & 0x3FFFu) * 32u + boff];
        uint4 u3 = htb4[(p3 & 0x3FFFu) * 32u + boff];
        a0 += c0 * bf2f_lo(u0.x) + c1 * bf2f_lo(u1.x) + c2 * bf2f_lo(u2.x) + c3 * bf2f_lo(u3.x);
        a1 += c0 * bf2f_hi(u0.x) + c1 * bf2f_hi(u1.x) + c2 * bf2f_hi(u2.x) + c3 * bf2f_hi(u3.x);
        a2 += c0 * bf2f_lo(u0.y) + c1 * bf2f_lo(u1.y) + c2 * bf2f_lo(u2.y) + c3 * bf2f_lo(u3.y);
        a3 += c0 * bf2f_hi(u0.y) + c1 * bf2f_hi(u1.y) + c2 * bf2f_hi(u2.y) + c3 * bf2f_hi(u3.y);
        a4 += c0 * bf2f_lo(u0.z) + c1 * bf2f_lo(u1.z) + c2 * bf2f_lo(u2.z) + c3 * bf2f_lo(u3.z);
        a5 += c0 * bf2f_hi(u0.z) + c1 * bf2f_hi(u1.z) + c2 * bf2f_hi(u2.z) + c3 * bf2f_hi(u3.z);
        a6 += c0 * bf2f_lo(u0.w) + c1 * bf2f_lo(u1.w) + c2 * bf2f_lo(u2.w) + c3 * bf2f_lo(u3.w);
        a7 += c0 * bf2f_hi(u0.w) + c1 * bf2f_hi(u1.w) + c2 * bf2f_hi(u2.w) + c3 * bf2f_hi(u3.w);
    }
    if (k < deg) {                         // at most one leftover slot per lane
        uint pr = s_eb[k];
        float cc = s_coef[(k << 4) | b];
        uint4 u = htb4[(pr & 0x3FFFu) * 32u + boff];
        a0 += cc * bf2f_lo(u.x); a1 += cc * bf2f_hi(u.x);
        a2 += cc * bf2f_lo(u.y); a3 += cc * bf2f_hi(u.y);
        a4 += cc * bf2f_lo(u.z); a5 += cc * bf2f_hi(u.z);
        a6 += cc * bf2f_lo(u.w); a7 += cc * bf2f_hi(u.w);
    }
    // reduce over qd (lane bits 3,4,5)
    a0 += __shfl_xor(a0, 8, 64); a0 += __shfl_xor(a0, 16, 64); a0 += __shfl_xor(a0, 32, 64);
    a1 += __shfl_xor(a1, 8, 64); a1 += __shfl_xor(a1, 16, 64); a1 += __shfl_xor(a1, 32, 64);
    a2 += __shfl_xor(a2, 8, 64); a2 += __shfl_xor(a2, 16, 64); a2 += __shfl_xor(a2, 32, 64);
    a3 += __shfl_xor(a3, 8, 64); a3 += __shfl_xor(a3, 16, 64); a3 += __shfl_xor(a3, 32, 64);
    a4 += __shfl_xor(a4, 8, 64); a4 += __shfl_xor(a4, 16, 64); a4 += __shfl_xor(a4, 32, 64);
    a5 += __shfl_xor(a5, 8, 64); a5 += __shfl_xor(a5, 16, 64); a5 += __shfl_xor(a5, 32, 64);
    a6 += __shfl_xor(a6, 8, 64); a6 += __shfl_xor(a6, 16, 64); a6 += __shfl_xor(a6, 32, 64);
    a7 += __shfl_xor(a7, 8, 64); a7 += __shfl_xor(a7, 16, 64); a7 += __shfl_xor(a7, 32, 64);
    if (qd == 0) {
        float inv = 1.0f / fmaxf((float)cnt, 1.0f);
        int cb = 8 * c8;
        s_feat[b][cb]     = a0 * amp_w[cb]     * inv;
        s_feat[b][cb + 1] = a1 * amp_w[cb + 1] * inv;
        s_feat[b][cb + 2] = a2 * amp_w[cb + 2] * inv;
        s_feat[b][cb + 3] = a3 * amp_w[cb + 3] * inv;
        s_feat[b][cb + 4] = a4 * amp_w[cb + 4] * inv;
        s_feat[b][cb + 5] = a5 * amp_w[cb + 5] * inv;
        s_feat[b][cb + 6] = a6 * amp_w[cb + 6] * inv;
        s_feat[b][cb + 7] = a7 * amp_w[cb + 7] * inv;
    }
    __syncthreads();

    // Dense 32->32; thread (bb, o2) produces channels (2*o2, 2*o2+1) -> float2.
    {
        int o2 = tid & 15, bb = tid >> 4;
        const float4* wr0 = (const float4*)&s_wmT[(2 * o2) * 36];
        const float4* wr1 = (const float4*)&s_wmT[(2 * o2 + 1) * 36];
        const float4* x4  = (const float4*)&s_x[bb][0];
        const float4* f4  = (const float4*)&s_feat[bb][0];
        float d0 = b2[2 * o2], d1 = b2[2 * o2 + 1];
        #pragma unroll
        for (int q = 0; q < 4; ++q) {
            float4 xv = x4[q], fv = f4[q];
            float4 w0a = wr0[q], w0b = wr0[4 + q];
            float4 w1a = wr1[q], w1b = wr1[4 + q];
            d0 += xv.x * w0a.x + xv.y * w0a.y + xv.z * w0a.z + xv.w * w0a.w;
            d0 += fv.x * w0b.x + fv.y * w0b.y + fv.z * w0b.z + fv.w * w0b.w;
            d1 += xv.x * w1a.x + xv.y * w1a.y + xv.z * w1a.z + xv.w * w1a.w;
            d1 += fv.x * w1b.x + fv.y * w1b.y + fv.z * w1b.z + fv.w * w1b.w;
        }
        size_t ob = ((size_t)bb * N + n) * 32;
        float2 r; r.x = d0; r.y = d1;
        *(float2*)(out + ob + 2 * o2) = r;
    }
}

// ---------------------------------------------------------------------------
extern "C" void kernel_launch(void* const* d_in, const int* in_sizes, int n_in,
                              void* d_out, int out_size, void* d_ws, size_t ws_size,
                              hipStream_t stream) {
    const float* X       = (const float*)d_in[0];
    const int*   ei1     = (const int*)  d_in[1];   // src=ei1, dst=ei1+E
    const float* ew1     = (const float*)d_in[2];
    const int*   ei2     = (const int*)  d_in[4];
    const float* ew2     = (const float*)d_in[5];
    const float* amp_w1  = (const float*)d_in[7];
    const float* gate_w1 = (const float*)d_in[8];
    const float* gate_b1 = (const float*)d_in[9];
    const float* w1      = (const float*)d_in[10];
    const float* b1      = (const float*)d_in[11];
    const float* amp_w2  = (const float*)d_in[12];
    const float* gate_w2 = (const float*)d_in[13];
    const float* gate_b2 = (const float*)d_in[14];
    const float* w2      = (const float*)d_in[15];
    const float* b2      = (const float*)d_in[16];
    float* out = (float*)d_out;

    // ws layout
    char* p = (char*)d_ws;
    ushort* yt     = (ushort*)p; p += (size_t)N * B * 16 * sizeof(ushort); // 5.12 MB
    ushort* htb    = (ushort*)p; p += (size_t)N * B * 16 * sizeof(ushort); // 5.12 MB
    float* xpart   = (float*)p;  p += (size_t)N * B * 16 * sizeof(float);  // 10.24 MB
    float* gi1     = (float*)p;  p += (size_t)N * B * sizeof(float);
    float* gj1     = (float*)p;  p += (size_t)N * B * sizeof(float);
    float* gi2     = (float*)p;  p += (size_t)N * B * sizeof(float);
    float* gj2     = (float*)p;  p += (size_t)N * B * sizeof(float);
    uint*  bucket1 = (uint*)p;   p += (size_t)N * CAP * sizeof(uint);      // 3.84 MB
    uint*  bucket2 = (uint*)p;   p += (size_t)N * CAP * sizeof(uint);      // 3.84 MB
    int*   bcount1 = (int*)p;    p += (size_t)N * sizeof(int);
    int*   bcount2 = (int*)p;    p += (size_t)N * sizeof(int);
    float* w2T     = (float*)p;  p += 1024 * sizeof(float);

    hipMemsetAsync(bcount1, 0, 2 * (size_t)N * sizeof(int), stream);
    prep_bucket_kernel<<<2048, 256, 0, stream>>>(
        X, gate_w1, amp_w1, b1, ei1, ew1, ei2, ew2, w1, w2,
        yt, xpart, gi1, gj1, w2T,
        bcount1, bucket1, bcount2, bucket2);

    agg1_kernel<<<N, 256, 0, stream>>>(
        (const uint4*)yt, xpart, gi1, gj1, bcount1, bucket1,
        gate_w1, gate_b1, gate_w2, htb, gi2, gj2);

    agg_dense2_kernel<<<N, 256, 0, stream>>>(
        (const uint4*)htb, gi2, gj2, bcount2, bucket2,
        gate_w2, gate_b2, amp_w2, w2T, b2, out);
}

// Round 6
// 201.878 us; speedup vs baseline: 1.0226x; 1.0226x over previous
//
#include <hip/hip_runtime.h>
#include <math.h>

#define B 16
#define N 10000
#define E 160000
#define CAP 96   // per-dst bucket capacity; deg ~ Poisson(16), P(deg>96) ~ 0

// float -> bf16 (RNE) stored as ushort
__device__ __forceinline__ ushort f2bf(float v) {
    uint u = __float_as_uint(v);
    u = (u + 0x7fffu + ((u >> 16) & 1u)) >> 16;
    return (ushort)u;
}
__device__ __forceinline__ float bf2f(ushort u) { return __uint_as_float(((uint)u) << 16); }
__device__ __forceinline__ float bf2f_lo(uint u) { return __uint_as_float(u << 16); }
__device__ __forceinline__ float bf2f_hi(uint u) { return __uint_as_float(u & 0xffff0000u); }
// bucket payload: (ew_q18 << 14) | src ; decode with midpoint
__device__ __forceinline__ float dec_ew(uint u) {
    return ((float)(u >> 14) + 0.5f) * (1.0f / 262144.0f);
}

// ---------------------------------------------------------------------------
// Bucket kernel: edge bucketing (atomics) + w2T transpose. Lean (~16 VGPR).
// ---------------------------------------------------------------------------
__global__ __launch_bounds__(256)
void bucket_kernel(const int* __restrict__ ei1, const float* __restrict__ ew1,
                   const int* __restrict__ ei2, const float* __restrict__ ew2,
                   const float* __restrict__ w2,        // (32,32)
                   float* __restrict__ w2T,
                   int* __restrict__ bcount1, uint* __restrict__ bucket1,
                   int* __restrict__ bcount2, uint* __restrict__ bucket2) {
    int gtid = blockIdx.x * 256 + threadIdx.x;
    int gs = gridDim.x * 256;

    for (int t = gtid; t < 2 * E; t += gs) {
        if (t < E) {
            int d = ei1[E + t];
            int pos = atomicAdd(&bcount1[d], 1);
            if (pos < CAP) {
                uint q = (uint)(ew1[t] * 262144.0f);
                if (q > 262143u) q = 262143u;
                bucket1[d * CAP + pos] = (q << 14) | (uint)ei1[t];
            }
        } else {
            int e = t - E;
            int d = ei2[E + e];
            int pos = atomicAdd(&bcount2[d], 1);
            if (pos < CAP) {
                uint q = (uint)(ew2[e] * 262144.0f);
                if (q > 262143u) q = 262143u;
                bucket2[d * CAP + pos] = (q << 14) | (uint)ei2[e];
            }
        }
    }

    // weight transpose for layer 2: w2T[o][kk] (32x32)
    if (gtid < 1024) {
        w2T[(gtid & 31) * 32 + (gtid >> 5)] = w2[gtid];
    }
}

// ---------------------------------------------------------------------------
// Row-prep kernel (R5 post-mortem: one-thread-per-row version hit 208 VGPR /
// 9% occupancy). One NODE per block, 256 threads = 16 batches x 16 outputs;
// X and w1 staged in LDS, each thread computes ONE (po, py) pair -> ~32 VGPR.
//   y[r=n*16+b][o]  = sum_c amp[c]*x[n,b,c]*w1[32+c][o]   (bf16)
//   xpart[r][o]     = sum_c x[n,b,c]*w1[c][o] + b1[o]     (fp32)
//   gi[r], gj[r]    = gate dots (16-lane shuffle reduce)
// ---------------------------------------------------------------------------
__global__ __launch_bounds__(256, 8)
void rowprep_kernel(const float* __restrict__ X,
                    const float* __restrict__ gate_w1,   // (65)
                    const float* __restrict__ amp_w1,    // (32)
                    const float* __restrict__ b1,        // (16)
                    const float* __restrict__ w1,        // (64,16)
                    ushort* __restrict__ yt,             // (N*16,16) bf16
                    float* __restrict__ xpart,           // (N*16,16) fp32
                    float* __restrict__ gi, float* __restrict__ gj) {
    __shared__ __align__(16) float s_w1[64 * 16];     // [c][o], 4 KB
    __shared__ float s_x[16][33];                     // [b][c], pad 33
    __shared__ float s_py[16][17];                    // [b][o], pad 17

    int n = blockIdx.x;
    int tid = threadIdx.x;

    {   // stage w1: 1 float4 per thread
        int i = tid * 4;
        *(float4*)&s_w1[i] = *(const float4*)&w1[i];
    }
    {   // stage X: 16-lane group per row, float2 each (128B contiguous/row)
        int b = tid >> 4, c2 = (tid & 15) * 2;
        float2 v = *(const float2*)(X + ((size_t)b * N + n) * 32 + c2);
        s_x[b][c2] = v.x; s_x[b][c2 + 1] = v.y;
    }
    __syncthreads();

    int b = tid >> 4, o = tid & 15;
    float po = b1[o], py = 0.f;
    #pragma unroll
    for (int c = 0; c < 32; ++c) {
        float xa = s_x[b][c];                 // broadcast within o-group
        po += xa * s_w1[c * 16 + o];
        py += amp_w1[c] * xa * s_w1[(32 + c) * 16 + o];
    }
    // gate dots: thread covers channels o and o+16, reduce over 16 lanes
    float pi = s_x[b][o] * gate_w1[o]      + s_x[b][o + 16] * gate_w1[o + 16];
    float pj = s_x[b][o] * gate_w1[32 + o] + s_x[b][o + 16] * gate_w1[48 + o];
    #pragma unroll
    for (int off = 8; off; off >>= 1) {
        pi += __shfl_xor(pi, off, 16);
        pj += __shfl_xor(pj, off, 16);
    }
    int r = n * 16 + b;
    xpart[(size_t)r * 16 + o] = po;           // 1KB/block, fully coalesced
    s_py[b][o] = py;
    if (o == 0) { gi[r] = pi; gj[r] = pj; }
    __syncthreads();

    if (tid < 64) {   // pack y rows: 4 threads/row, uint2 each (512B/block)
        int bb = tid >> 2, j = tid & 3;
        uint lo = (uint)f2bf(s_py[bb][4 * j])     | ((uint)f2bf(s_py[bb][4 * j + 1]) << 16);
        uint hi = (uint)f2bf(s_py[bb][4 * j + 2]) | ((uint)f2bf(s_py[bb][4 * j + 3]) << 16);
        ((uint2*)yt)[(size_t)(n * 16 + bb) * 4 + j] = make_uint2(lo, hi);
    }
}

// ---------------------------------------------------------------------------
// Fused layer 1 (y-precompute form): one node per block, 256 threads.
// Phases: [eb+gi stage | coef | gather y + h-reduce | register epilogue].
// No weights, no X, no dense matmul, 6.6 KB LDS. (Unchanged from R5.)
// ---------------------------------------------------------------------------
__global__ __launch_bounds__(256, 8)
void agg1_kernel(const uint4* __restrict__ y4,      // (N*16,16) bf16 as uint4 x2/row
                 const float* __restrict__ xpart,   // (N*16,16) fp32
                 const float* __restrict__ gi,
                 const float* __restrict__ gj,
                 const int* __restrict__ bcount,
                 const uint* __restrict__ bucket,
                 const float* __restrict__ gate_w,   // (65), [64]=wge
                 const float* __restrict__ gate_b,
                 const float* __restrict__ gate_w2,  // (33)
                 ushort* __restrict__ htb,
                 float* __restrict__ gi2, float* __restrict__ gj2) {
    __shared__ uint  s_eb[CAP];
    __shared__ float s_coef[CAP * 16];                // 6 KB
    __shared__ float s_gi[16];

    int n = blockIdx.x;
    int tid = threadIdx.x;

    int cnt = bcount[n];
    int deg = cnt < CAP ? cnt : CAP;
    if (tid < CAP / 4)
        ((uint4*)s_eb)[tid] = ((const uint4*)(bucket + (size_t)n * CAP))[tid];
    if (tid < 16) s_gi[tid] = gi[n * 16 + tid] + gate_b[0];
    __syncthreads();

    // coef[k][b] = ew * sigmoid(gi + gj + ew*wge + gb)
    float wge = gate_w[64];
    for (int p = tid; p < deg * 16; p += 256) {
        int k = p >> 4, b = p & 15;
        uint pr = s_eb[k];
        float w = dec_ew(pr);
        float z = s_gi[b] + gj[(pr & 0x3FFFu) * 16 + b] + w * wge;
        s_coef[p] = w / (1.0f + __expf(-z));
    }
    __syncthreads();

    // gather y: acc[o] = sum_k coef[k,b] * y[src_k, b, o-slice]
    int wv = tid >> 6, l = tid & 63;
    int og = l & 1;                        // o-slice: 8*og .. 8*og+7
    int b  = 4 * wv + ((l >> 1) & 3);      // 0..15
    int h  = l >> 3;                       // slot offset 0..7
    uint boff = (uint)b * 2 + og;          // uint4 idx within 32B row pair
    float a0 = 0.f, a1 = 0.f, a2 = 0.f, a3 = 0.f;
    float a4 = 0.f, a5 = 0.f, a6 = 0.f, a7 = 0.f;
    for (int k = h; k < deg; k += 8) {
        uint pr = s_eb[k];
        float cc = s_coef[(k << 4) | b];
        uint4 u = y4[(pr & 0x3FFFu) * 32u + boff];
        a0 += cc * bf2f_lo(u.x); a1 += cc * bf2f_hi(u.x);
        a2 += cc * bf2f_lo(u.y); a3 += cc * bf2f_hi(u.y);
        a4 += cc * bf2f_lo(u.z); a5 += cc * bf2f_hi(u.z);
        a6 += cc * bf2f_lo(u.w); a7 += cc * bf2f_hi(u.w);
    }
    // reduce over h (lane bits 3,4,5)
    a0 += __shfl_xor(a0, 8, 64); a0 += __shfl_xor(a0, 16, 64); a0 += __shfl_xor(a0, 32, 64);
    a1 += __shfl_xor(a1, 8, 64); a1 += __shfl_xor(a1, 16, 64); a1 += __shfl_xor(a1, 32, 64);
    a2 += __shfl_xor(a2, 8, 64); a2 += __shfl_xor(a2, 16, 64); a2 += __shfl_xor(a2, 32, 64);
    a3 += __shfl_xor(a3, 8, 64); a3 += __shfl_xor(a3, 16, 64); a3 += __shfl_xor(a3, 32, 64);
    a4 += __shfl_xor(a4, 8, 64); a4 += __shfl_xor(a4, 16, 64); a4 += __shfl_xor(a4, 32, 64);
    a5 += __shfl_xor(a5, 8, 64); a5 += __shfl_xor(a5, 16, 64); a5 += __shfl_xor(a5, 32, 64);
    a6 += __shfl_xor(a6, 8, 64); a6 += __shfl_xor(a6, 16, 64); a6 += __shfl_xor(a6, 32, 64);
    a7 += __shfl_xor(a7, 8, 64); a7 += __shfl_xor(a7, 16, 64); a7 += __shfl_xor(a7, 32, 64);

    if (h == 0) {   // 8 lanes/wave: 4 b x 2 og
        float inv = 1.0f / fmaxf((float)cnt, 1.0f);
        size_t xb = ((size_t)n * 16 + b) * 16 + 8 * og;
        float4 xp0 = *(const float4*)&xpart[xb];
        float4 xp1 = *(const float4*)&xpart[xb + 4];
        float v0 = xp0.x + inv * a0, v1 = xp0.y + inv * a1;
        float v2 = xp0.z + inv * a2, v3 = xp0.w + inv * a3;
        float v4 = xp1.x + inv * a4, v5 = xp1.y + inv * a5;
        float v6 = xp1.z + inv * a6, v7 = xp1.w + inv * a7;
        v0 = v0 > 0.f ? v0 : 0.01f * v0;  v1 = v1 > 0.f ? v1 : 0.01f * v1;
        v2 = v2 > 0.f ? v2 : 0.01f * v2;  v3 = v3 > 0.f ? v3 : 0.01f * v3;
        v4 = v4 > 0.f ? v4 : 0.01f * v4;  v5 = v5 > 0.f ? v5 : 0.01f * v5;
        v6 = v6 > 0.f ? v6 : 0.01f * v6;  v7 = v7 > 0.f ? v7 : 0.01f * v7;
        uint4 pk;
        pk.x = (uint)f2bf(v0) | ((uint)f2bf(v1) << 16);
        pk.y = (uint)f2bf(v2) | ((uint)f2bf(v3) << 16);
        pk.z = (uint)f2bf(v4) | ((uint)f2bf(v5) << 16);
        pk.w = (uint)f2bf(v6) | ((uint)f2bf(v7) << 16);
        ((uint4*)htb)[(size_t)n * 32 + boff] = pk;
        int ob = 8 * og;
        float pi = v0 * gate_w2[ob]     + v1 * gate_w2[ob + 1]
                 + v2 * gate_w2[ob + 2] + v3 * gate_w2[ob + 3]
                 + v4 * gate_w2[ob + 4] + v5 * gate_w2[ob + 5]
                 + v6 * gate_w2[ob + 6] + v7 * gate_w2[ob + 7];
        float pj = v0 * gate_w2[16 + ob]     + v1 * gate_w2[16 + ob + 1]
                 + v2 * gate_w2[16 + ob + 2] + v3 * gate_w2[16 + ob + 3]
                 + v4 * gate_w2[16 + ob + 4] + v5 * gate_w2[16 + ob + 5]
                 + v6 * gate_w2[16 + ob + 6] + v7 * gate_w2[16 + ob + 7];
        pi += __shfl_xor(pi, 1, 64);
        pj += __shfl_xor(pj, 1, 64);
        if (og == 0) { gi2[n * 16 + b] = pi; gj2[n * 16 + b] = pj; }
    }
}

// ---------------------------------------------------------------------------
// Fused layer 2: one node per block, 256 threads, uint4 gather with 4 loads
// in flight (unchanged from R4/R5).
// ---------------------------------------------------------------------------
__global__ __launch_bounds__(256, 8)
void agg_dense2_kernel(const uint4* __restrict__ htb4,    // bf16x8 (16B)
                       const float* __restrict__ gi,
                       const float* __restrict__ gj,
                       const int* __restrict__ bcount,
                       const uint* __restrict__ bucket,
                       const float* __restrict__ gate_w,   // (33), [32]=wge
                       const float* __restrict__ gate_b,
                       const float* __restrict__ amp_w,    // (16)
                       const float* __restrict__ w2T,      // (32,32) [o][kk]
                       const float* __restrict__ b2,       // (32)
                       float* __restrict__ out) {
    __shared__ uint  s_eb[CAP];
    __shared__ float s_coef[CAP * 16];
    __shared__ float s_gi[16];
    __shared__ __align__(16) float s_x[16][20];       // row 80B: b128-able
    __shared__ __align__(16) float s_feat[16][20];
    __shared__ __align__(16) float s_wmT[32 * 36];    // [o][kk], row 144B

    int n = blockIdx.x;
    int tid = threadIdx.x;

    int cnt = bcount[n];
    int deg = cnt < CAP ? cnt : CAP;
    if (tid < CAP / 4)
        ((uint4*)s_eb)[tid] = ((const uint4*)(bucket + (size_t)n * CAP))[tid];
    {   // w2T staging: 256 float4 loads
        int o = tid >> 3, k4 = tid & 7;
        *(float4*)&s_wmT[o * 36 + k4 * 4] = ((const float4*)w2T)[o * 8 + k4];
    }
    if (tid < 32) {   // self features: 32 uint4 loads, decode to fp32 LDS
        uint4 u = htb4[(size_t)n * 32 + tid];
        int b = tid >> 1, cb = (tid & 1) * 8;
        float4 f0, f1;
        f0.x = bf2f_lo(u.x); f0.y = bf2f_hi(u.x);
        f0.z = bf2f_lo(u.y); f0.w = bf2f_hi(u.y);
        f1.x = bf2f_lo(u.z); f1.y = bf2f_hi(u.z);
        f1.z = bf2f_lo(u.w); f1.w = bf2f_hi(u.w);
        *(float4*)&s_x[b][cb]     = f0;
        *(float4*)&s_x[b][cb + 4] = f1;
    }
    if (tid < 16) s_gi[tid] = gi[n * 16 + tid] + gate_b[0];
    __syncthreads();

    float wge = gate_w[32];
    for (int p = tid; p < deg * 16; p += 256) {
        int k = p >> 4, b = p & 15;
        uint pr = s_eb[k];
        float w = dec_ew(pr);
        float z = s_gi[b] + gj[(pr & 0x3FFFu) * 16 + b] + w * wge;
        s_coef[p] = w / (1.0f + __expf(-z));
    }
    __syncthreads();

    // Gather: c8=l&1, b=4*wv+((l>>1)&3), qd=l>>3 (slot depth 8), stride 32.
    int wv = tid >> 6, l = tid & 63;
    int c8 = l & 1;                        // channel group: 8c8..8c8+7
    int b  = 4 * wv + ((l >> 1) & 3);      // 0..15
    int qd = l >> 3;                       // slot offset 0..7
    uint boff = (uint)b * 2 + c8;          // uint4 idx within 512B node block
    float a0 = 0.f, a1 = 0.f, a2 = 0.f, a3 = 0.f;
    float a4 = 0.f, a5 = 0.f, a6 = 0.f, a7 = 0.f;
    int k = qd;
    for (; k + 8 < deg; k += 32) {         // slots k, k+8 valid; k+16, k+24 masked
        bool v2 = (k + 16) < deg, v3 = (k + 24) < deg;
        uint i2 = v2 ? (uint)(k + 16) : 0u;
        uint i3 = v3 ? (uint)(k + 24) : 0u;
        uint p0 = s_eb[k], p1 = s_eb[k + 8], p2 = s_eb[i2], p3 = s_eb[i3];
        float c0 = s_coef[(k << 4) | b];
        float c1 = s_coef[((k + 8) << 4) | b];
        float c2 = s_coef[(i2 << 4) | b]; if (!v2) c2 = 0.f;
        float c3 = s_coef[(i3 << 4) | b]; if (!v3) c3 = 0.f;
        uint4 u0 = htb4[(p0 & 0x3FFFu) * 32u + boff];
        uint4 u1 = htb4[(p1 & 0x3FFFu) * 32u + boff];
        uint4 u2 = htb4[(p2 & 0x3FFFu) * 32u + boff];
        uint4 u3 = htb4[(p3 & 0x3FFFu) * 32u + boff];
        a0 += c0 * bf2f_lo(u0.x) + c1 * bf2f_lo(u1.x) + c2 * bf2f_lo(u2.x) + c3 * bf2f_lo(u3.x);
        a1 += c0 * bf2f_hi(u0.x) + c1 * bf2f_hi(u1.x) + c2 * bf2f_hi(u2.x) + c3 * bf2f_hi(u3.x);
        a2 += c0 * bf2f_lo(u0.y) + c1 * bf2f_lo(u1.y) + c2 * bf2f_lo(u2.y) + c3 * bf2f_lo(u3.y);
        a3 += c0 * bf2f_hi(u0.y) + c1 * bf2f_hi(u1.y) + c2 * bf2f_hi(u2.y) + c3 * bf2f_hi(u3.y);
        a4 += c0 * bf2f_lo(u0.z) + c1 * bf2f_lo(u1.z) + c2 * bf2f_lo(u2.z) + c3 * bf2f_lo(u3.z);
        a5 += c0 * bf2f_hi(u0.z) + c1 * bf2f_hi(u1.z) + c2 * bf2f_hi(u2.z) + c3 * bf2f_hi(u3.z);
        a6 += c0 * bf2f_lo(u0.w) + c1 * bf2f_lo(u1.w) + c2 * bf2f_lo(u2.w) + c3 * bf2f_lo(u3.w);
        a7 += c0 * bf2f_hi(u0.w) + c1 * bf2f_hi(u1.w) + c2 * bf2f_hi(u2.w) + c3 * bf2f_hi(u3.w);
    }
    if (k < deg) {                         // at most one leftover slot per lane
        uint pr = s_eb[k];
        float cc = s_coef[(k << 4) | b];
        uint4 u = htb4[(pr & 0x3FFFu) * 32u + boff];
        a0 += cc * bf2f_lo(u.x); a1 += cc * bf2f_hi(u.x);
        a2 += cc * bf2f_lo(u.y); a3 += cc * bf2f_hi(u.y);
        a4 += cc * bf2f_lo(u.z); a5 += cc * bf2f_hi(u.z);
        a6 += cc * bf2f_lo(u.w); a7 += cc * bf2f_hi(u.w);
    }
    // reduce over qd (lane bits 3,4,5)
    a0 += __shfl_xor(a0, 8, 64); a0 += __shfl_xor(a0, 16, 64); a0 += __shfl_xor(a0, 32, 64);
    a1 += __shfl_xor(a1, 8, 64); a1 += __shfl_xor(a1, 16, 64); a1 += __shfl_xor(a1, 32, 64);
    a2 += __shfl_xor(a2, 8, 64); a2 += __shfl_xor(a2, 16, 64); a2 += __shfl_xor(a2, 32, 64);
    a3 += __shfl_xor(a3, 8, 64); a3 += __shfl_xor(a3, 16, 64); a3 += __shfl_xor(a3, 32, 64);
    a4 += __shfl_xor(a4, 8, 64); a4 += __shfl_xor(a4, 16, 64); a4 += __shfl_xor(a4, 32, 64);
    a5 += __shfl_xor(a5, 8, 64); a5 += __shfl_xor(a5, 16, 64); a5 += __shfl_xor(a5, 32, 64);
    a6 += __shfl_xor(a6, 8, 64); a6 += __shfl_xor(a6, 16, 64); a6 += __shfl_xor(a6, 32, 64);
    a7 += __shfl_xor(a7, 8, 64); a7 += __shfl_xor(a7, 16, 64); a7 += __shfl_xor(a7, 32, 64);
    if (qd == 0) {
        float inv = 1.0f / fmaxf((float)cnt, 1.0f);
        int cb = 8 * c8;
        s_feat[b][cb]     = a0 * amp_w[cb]     * inv;
        s_feat[b][cb + 1] = a1 * amp_w[cb + 1] * inv;
        s_feat[b][cb + 2] = a2 * amp_w[cb + 2] * inv;
        s_feat[b][cb + 3] = a3 * amp_w[cb + 3] * inv;
        s_feat[b][cb + 4] = a4 * amp_w[cb + 4] * inv;
        s_feat[b][cb + 5] = a5 * amp_w[cb + 5] * inv;
        s_feat[b][cb + 6] = a6 * amp_w[cb + 6] * inv;
        s_feat[b][cb + 7] = a7 * amp_w[cb + 7] * inv;
    }
    __syncthreads();

    // Dense 32->32; thread (bb, o2) produces channels (2*o2, 2*o2+1) -> float2.
    {
        int o2 = tid & 15, bb = tid >> 4;
        const float4* wr0 = (const float4*)&s_wmT[(2 * o2) * 36];
        const float4* wr1 = (const float4*)&s_wmT[(2 * o2 + 1) * 36];
        const float4* x4  = (const float4*)&s_x[bb][0];
        const float4* f4  = (const float4*)&s_feat[bb][0];
        float d0 = b2[2 * o2], d1 = b2[2 * o2 + 1];
        #pragma unroll
        for (int q = 0; q < 4; ++q) {
            float4 xv = x4[q], fv = f4[q];
            float4 w0a = wr0[q], w0b = wr0[4 + q];
            float4 w1a = wr1[q], w1b = wr1[4 + q];
            d0 += xv.x * w0a.x + xv.y * w0a.y + xv.z * w0a.z + xv.w * w0a.w;
            d0 += fv.x * w0b.x + fv.y * w0b.y + fv.z * w0b.z + fv.w * w0b.w;
            d1 += xv.x * w1a.x + xv.y * w1a.y + xv.z * w1a.z + xv.w * w1a.w;
            d1 += fv.x * w1b.x + fv.y * w1b.y + fv.z * w1b.z + fv.w * w1b.w;
        }
        size_t ob = ((size_t)bb * N + n) * 32;
        float2 r; r.x = d0; r.y = d1;
        *(float2*)(out + ob + 2 * o2) = r;
    }
}

// ---------------------------------------------------------------------------
extern "C" void kernel_launch(void* const* d_in, const int* in_sizes, int n_in,
                              void* d_out, int out_size, void* d_ws, size_t ws_size,
                              hipStream_t stream) {
    const float* X       = (const float*)d_in[0];
    const int*   ei1     = (const int*)  d_in[1];   // src=ei1, dst=ei1+E
    const float* ew1     = (const float*)d_in[2];
    const int*   ei2     = (const int*)  d_in[4];
    const float* ew2     = (const float*)d_in[5];
    const float* amp_w1  = (const float*)d_in[7];
    const float* gate_w1 = (const float*)d_in[8];
    const float* gate_b1 = (const float*)d_in[9];
    const float* w1      = (const float*)d_in[10];
    const float* b1      = (const float*)d_in[11];
    const float* amp_w2  = (const float*)d_in[12];
    const float* gate_w2 = (const float*)d_in[13];
    const float* gate_b2 = (const float*)d_in[14];
    const float* w2      = (const float*)d_in[15];
    const float* b2      = (const float*)d_in[16];
    float* out = (float*)d_out;

    // ws layout
    char* p = (char*)d_ws;
    ushort* yt     = (ushort*)p; p += (size_t)N * B * 16 * sizeof(ushort); // 5.12 MB
    ushort* htb    = (ushort*)p; p += (size_t)N * B * 16 * sizeof(ushort); // 5.12 MB
    float* xpart   = (float*)p;  p += (size_t)N * B * 16 * sizeof(float);  // 10.24 MB
    float* gi1     = (float*)p;  p += (size_t)N * B * sizeof(float);
    float* gj1     = (float*)p;  p += (size_t)N * B * sizeof(float);
    float* gi2     = (float*)p;  p += (size_t)N * B * sizeof(float);
    float* gj2     = (float*)p;  p += (size_t)N * B * sizeof(float);
    uint*  bucket1 = (uint*)p;   p += (size_t)N * CAP * sizeof(uint);      // 3.84 MB
    uint*  bucket2 = (uint*)p;   p += (size_t)N * CAP * sizeof(uint);      // 3.84 MB
    int*   bcount1 = (int*)p;    p += (size_t)N * sizeof(int);
    int*   bcount2 = (int*)p;    p += (size_t)N * sizeof(int);
    float* w2T     = (float*)p;  p += 1024 * sizeof(float);

    hipMemsetAsync(bcount1, 0, 2 * (size_t)N * sizeof(int), stream);
    bucket_kernel<<<2048, 256, 0, stream>>>(
        ei1, ew1, ei2, ew2, w2, w2T,
        bcount1, bucket1, bcount2, bucket2);

    rowprep_kernel<<<N, 256, 0, stream>>>(
        X, gate_w1, amp_w1, b1, w1, yt, xpart, gi1, gj1);

    agg1_kernel<<<N, 256, 0, stream>>>(
        (const uint4*)yt, xpart, gi1, gj1, bcount1, bucket1,
        gate_w1, gate_b1, gate_w2, htb, gi2, gj2);

    agg_dense2_kernel<<<N, 256, 0, stream>>>(
        (const uint4*)htb, gi2, gj2, bcount2, bucket2,
        gate_w2, gate_b2, amp_w2, w2T, b2, out);
}